// Round 1
// baseline (43.324 us; speedup 1.0000x reference)
//
#include <hip/hip_runtime.h>
#include <math.h>

#define SEQ 8192
#define HID 2048

// ---------------------------------------------------------------------------
// Kernel 1: fused matvecs.
//   blocks [0, 512):   m[j] = W_pq[j,:] . pool + b_pq[j]      (one wave/row)
//   blocks [512, 768): v[k] += sum_{j in chunk} hidden[j]*W_qh[j,k]  (atomic)
// ---------------------------------------------------------------------------
__global__ __launch_bounds__(256) void k_mv(const float* __restrict__ pool,
                                            const float* __restrict__ W_pq,
                                            const float* __restrict__ b_pq,
                                            const float* __restrict__ hidden,
                                            const float* __restrict__ W_qh,
                                            float* __restrict__ m,
                                            float* __restrict__ v) {
    const int bid  = blockIdx.x;
    const int wave = threadIdx.x >> 6;
    const int lane = threadIdx.x & 63;

    if (bid < 512) {
        // ---- m = W_pq @ pool + b_pq : one wave per row, coalesced float4 ----
        const int row = bid * 4 + wave;            // < 2048
        const float4* Wrow = reinterpret_cast<const float4*>(W_pq + (size_t)row * HID);
        const float4* p4   = reinterpret_cast<const float4*>(pool);
        float acc = 0.f;
        #pragma unroll
        for (int i = lane; i < HID / 4; i += 64) {
            float4 w = Wrow[i];
            float4 p = p4[i];
            acc += w.x * p.x + w.y * p.y + w.z * p.z + w.w * p.w;
        }
        #pragma unroll
        for (int off = 32; off; off >>= 1) acc += __shfl_down(acc, off, 64);
        if (lane == 0) m[row] = acc + b_pq[row];
    } else {
        // ---- v[k] = sum_j hidden[j] * W_qh[j,k] : column reduction ----
        // 2 column tiles (1024 floats each via float4) x 128 row chunks (16 rows)
        const int b      = bid - 512;              // 0..255
        const int ctile  = b & 1;
        const int rchunk = b >> 1;
        const int c4     = ctile * 256 + threadIdx.x;   // float4 column index
        const int r0     = rchunk * 16;
        float4 acc = {0.f, 0.f, 0.f, 0.f};
        #pragma unroll
        for (int r = r0; r < r0 + 16; ++r) {
            const float h  = hidden[r];
            const float4 w = reinterpret_cast<const float4*>(W_qh + (size_t)r * HID)[c4];
            acc.x += h * w.x; acc.y += h * w.y; acc.z += h * w.z; acc.w += h * w.w;
        }
        atomicAdd(&v[c4 * 4 + 0], acc.x);
        atomicAdd(&v[c4 * 4 + 1], acc.y);
        atomicAdd(&v[c4 * 4 + 2], acc.z);
        atomicAdd(&v[c4 * 4 + 3], acc.w);
    }
}

// ---------------------------------------------------------------------------
// Kernel 2: energies[s] = enc[s,:] . (m * v)   — one wave per row
// ---------------------------------------------------------------------------
__global__ __launch_bounds__(256) void k_energy(const float* __restrict__ enc,
                                                const float* __restrict__ m,
                                                const float* __restrict__ v,
                                                float* __restrict__ energies) {
    const int wave = threadIdx.x >> 6;
    const int lane = threadIdx.x & 63;
    const int row  = blockIdx.x * 4 + wave;        // < 8192
    const float4* E  = reinterpret_cast<const float4*>(enc + (size_t)row * HID);
    const float4* m4 = reinterpret_cast<const float4*>(m);
    const float4* v4 = reinterpret_cast<const float4*>(v);
    float acc = 0.f;
    #pragma unroll
    for (int i = lane; i < HID / 4; i += 64) {
        float4 e = E[i];
        float4 a = m4[i];
        float4 b = v4[i];
        acc += e.x * a.x * b.x + e.y * a.y * b.y + e.z * a.z * b.z + e.w * a.w * b.w;
    }
    #pragma unroll
    for (int off = 32; off; off >>= 1) acc += __shfl_down(acc, off, 64);
    if (lane == 0) energies[row] = acc;
}

// ---------------------------------------------------------------------------
// Kernel 3: softmax over 8192 elements — single block, 1024 threads x 8 elems
// ---------------------------------------------------------------------------
__global__ __launch_bounds__(1024) void k_softmax(const float* __restrict__ e,
                                                  float* __restrict__ out) {
    __shared__ float red[16];
    const int tid  = threadIdx.x;
    const int wave = tid >> 6;
    const int lane = tid & 63;

    float vals[8];
    float mx = -INFINITY;
    #pragma unroll
    for (int i = 0; i < 8; ++i) {
        vals[i] = e[tid + i * 1024];
        mx = fmaxf(mx, vals[i]);
    }
    #pragma unroll
    for (int off = 32; off; off >>= 1) mx = fmaxf(mx, __shfl_down(mx, off, 64));
    if (lane == 0) red[wave] = mx;
    __syncthreads();
    if (tid < 64) {
        float t = (tid < 16) ? red[tid] : -INFINITY;
        #pragma unroll
        for (int off = 8; off; off >>= 1) t = fmaxf(t, __shfl_down(t, off, 64));
        if (tid == 0) red[0] = t;
    }
    __syncthreads();
    mx = red[0];
    __syncthreads();   // red[0] consumed before reuse below

    float s = 0.f;
    #pragma unroll
    for (int i = 0; i < 8; ++i) {
        vals[i] = expf(vals[i] - mx);
        s += vals[i];
    }
    #pragma unroll
    for (int off = 32; off; off >>= 1) s += __shfl_down(s, off, 64);
    if (lane == 0) red[wave] = s;
    __syncthreads();
    if (tid < 64) {
        float t = (tid < 16) ? red[tid] : 0.f;
        #pragma unroll
        for (int off = 8; off; off >>= 1) t += __shfl_down(t, off, 64);
        if (tid == 0) red[0] = t;
    }
    __syncthreads();
    const float inv = 1.f / red[0];
    #pragma unroll
    for (int i = 0; i < 8; ++i) out[tid + i * 1024] = vals[i] * inv;
}

// ---------------------------------------------------------------------------
extern "C" void kernel_launch(void* const* d_in, const int* in_sizes, int n_in,
                              void* d_out, int out_size, void* d_ws, size_t ws_size,
                              hipStream_t stream) {
    const float* hidden = (const float*)d_in[0];   // (1, 2048)
    const float* enc    = (const float*)d_in[1];   // (8192, 2048)
    const float* pool   = (const float*)d_in[2];   // (1, 2048)
    const float* W_pq   = (const float*)d_in[3];   // (2048, 2048)
    const float* b_pq   = (const float*)d_in[4];   // (2048,)
    const float* W_qh   = (const float*)d_in[5];   // (2048, 2048)
    // d_in[6] = b_qh — drops out of softmax (uniform shift), unused.

    float* ws       = (float*)d_ws;
    float* m        = ws;            // 2048
    float* v        = ws + HID;      // 2048
    float* energies = ws + 2 * HID;  // 8192
    float* out      = (float*)d_out; // 8192

    // v is accumulated with atomics — must start from zero every call.
    hipMemsetAsync(v, 0, HID * sizeof(float), stream);

    k_mv<<<dim3(512 + 256), dim3(256), 0, stream>>>(pool, W_pq, b_pq, hidden, W_qh, m, v);
    k_energy<<<dim3(SEQ / 4), dim3(256), 0, stream>>>(enc, m, v, energies);
    k_softmax<<<dim3(1), dim3(1024), 0, stream>>>(energies, out);
}